// Round 12
// baseline (173.143 us; speedup 1.0000x reference)
//
#include <hip/hip_runtime.h>
#include <math.h>

// Problem constants (fixed by the reference)
#define DM   1024
#define SEQ  2048
#define BAT  4
#define NH   16
#define DH   64
#define MTOT (BAT*SEQ)   // 8192 rows
#define NKT  (SEQ/64)    // 32 key tiles

typedef __attribute__((ext_vector_type(8))) short bf16x8;   // 8 bf16 = 4 VGPR (MFMA A/B frag)
typedef __attribute__((ext_vector_type(4))) short bf16x4;
typedef __attribute__((ext_vector_type(4))) float f32x4;    // 16x16 MFMA C/D frag
typedef __attribute__((ext_vector_type(16))) float f32x16;  // 32x32 MFMA C/D frag
typedef __attribute__((ext_vector_type(4))) unsigned int u32x4;

// scores pre-scaled into exp2 domain: 1/sqrt(64) * log2(e)
#define QSCALE 0.18033688011112042f

static __device__ __forceinline__ unsigned short f2bf(float f) {
    union { float f; unsigned u; } x; x.f = f;
    unsigned r = x.u + 0x7fffu + ((x.u >> 16) & 1u);   // RNE
    return (unsigned short)(r >> 16);
}

// hardware exp2 (v_exp_f32) — avoid __exp2f, which collides with glibc math.h
static __device__ __forceinline__ float hexp2(float x) {
    return __builtin_amdgcn_exp2f(x);
}

static __device__ __forceinline__ void load_lds16(const void* g, void* l) {
    __builtin_amdgcn_global_load_lds(
        (const __attribute__((address_space(1))) unsigned int*)g,
        (__attribute__((address_space(3))) unsigned int*)l,
        16, 0, 0);
}

// ---------------------------------------------------------------------------
// Kernel 0a: x (fp32) -> bf16, elementwise
// ---------------------------------------------------------------------------
__global__ __launch_bounds__(256)
void xcvt(const float* __restrict__ x, unsigned short* __restrict__ out, int n8)
{
    for (int i = blockIdx.x * blockDim.x + threadIdx.x; i < n8; i += gridDim.x * blockDim.x) {
        float4 a = reinterpret_cast<const float4*>(x)[2 * i];
        float4 b = reinterpret_cast<const float4*>(x)[2 * i + 1];
        ushort4 lo, hi;
        lo.x = f2bf(a.x); lo.y = f2bf(a.y); lo.z = f2bf(a.z); lo.w = f2bf(a.w);
        hi.x = f2bf(b.x); hi.y = f2bf(b.y); hi.z = f2bf(b.z); hi.w = f2bf(b.w);
        reinterpret_cast<ushort4*>(out)[2 * i]     = lo;
        reinterpret_cast<ushort4*>(out)[2 * i + 1] = hi;
    }
}

// ---------------------------------------------------------------------------
// Kernel 0b: W[k][n] fp32 -> Wt[n][k] bf16 (per projection), Wt[3072][1024].
// ---------------------------------------------------------------------------
__global__ __launch_bounds__(256)
void wtcvt(const float* __restrict__ Wq, const float* __restrict__ Wk,
           const float* __restrict__ Wv, unsigned short* __restrict__ Wt)
{
    const float* W = (blockIdx.z == 0) ? Wq : (blockIdx.z == 1) ? Wk : Wv;
    unsigned short* out = Wt + (size_t)blockIdx.z * DM * DM;

    __shared__ float Ts[64][65];   // Ts[k][n]
    const int t  = threadIdx.x;
    const int k0 = blockIdx.y * 64;
    const int n0 = blockIdx.x * 64;

    const int r  = t >> 4;
    const int c4 = (t & 15) * 4;
#pragma unroll
    for (int u = 0; u < 4; ++u) {
        float4 v = *reinterpret_cast<const float4*>(&W[(size_t)(k0 + r + u * 16) * DM + n0 + c4]);
        Ts[r + u * 16][c4 + 0] = v.x;
        Ts[r + u * 16][c4 + 1] = v.y;
        Ts[r + u * 16][c4 + 2] = v.z;
        Ts[r + u * 16][c4 + 3] = v.w;
    }
    __syncthreads();

    const int n   = t >> 2;
    const int kk0 = (t & 3) * 16;
#pragma unroll
    for (int j = 0; j < 4; ++j) {
        ushort4 o;
        o.x = f2bf(Ts[kk0 + j * 4 + 0][n]);
        o.y = f2bf(Ts[kk0 + j * 4 + 1][n]);
        o.z = f2bf(Ts[kk0 + j * 4 + 2][n]);
        o.w = f2bf(Ts[kk0 + j * 4 + 3][n]);
        *reinterpret_cast<ushort4*>(&out[(size_t)(n0 + n) * DM + k0 + kk0 + j * 4]) = o;
    }
}

// ---------------------------------------------------------------------------
// Kernel 1: QKV projection GEMM, bf16 MFMA (16x16x32), fp32 accumulate.
// THIS ROUND: single-barrier mid-stage pipeline (r11-attn-proven transform):
//   per K-step: __syncthreads (drains GSTAGE(kt) issued last iter, orders WAR)
//               -> compute ks=0 on buf[cb] -> GSTAGE(kt+1 -> cb^1)
//               -> compute ks=1 on buf[cb]
// The HBM staging latency (~900cyc) now drains a full compute phase after
// issue instead of immediately (the m97 ~20% barrier-drain stall), and one
// of two barriers per K-step is removed. Pure __syncthreads sync only.
// ---------------------------------------------------------------------------
#define GBM 128
#define GBN 128
#define GBK 64
#define GNT (DM/GBK)

__global__ __launch_bounds__(256)
void qkv_mfma(const unsigned short* __restrict__ Xb,
              const unsigned short* __restrict__ Wt,
              const float* __restrict__ bq, const float* __restrict__ bk,
              const float* __restrict__ bv,
              unsigned short* __restrict__ Qw, unsigned short* __restrict__ Kw,
              unsigned short* __restrict__ Vt)
{
    __shared__ __align__(16) unsigned short As[2][GBM][GBK];
    __shared__ __align__(16) unsigned short Bs[2][GBN][GBK];

    const int t    = threadIdx.x;
    const int lane = t & 63;
    const int w    = t >> 6;
    const int g    = lane >> 4;
    const int c    = lane & 15;
    const int wm   = w >> 1;
    const int wn   = w & 1;

    const int cpx = gridDim.x >> 3;
    const int swz = (blockIdx.x & 7) * cpx + (blockIdx.x >> 3);
    const int tn  = swz % (3072 / GBN);
    const int tm  = swz / (3072 / GBN);
    const int m0  = tm * GBM;
    const int n0  = tn * GBN;

    const int srow  = lane >> 3;
    const int sswz  = ((lane & 7) * 16) ^ (16 * (srow & 7));
    const int rbase = w * 32;

#define GSTAGE(buf, kt)                                                               \
    do {                                                                              \
        const size_t kb = (size_t)(kt) * GBK;                                         \
        _Pragma("unroll")                                                             \
        for (int u = 0; u < 4; ++u) {                                                 \
            const int row = rbase + u * 8;                                            \
            load_lds16((const char*)(Xb + (size_t)(m0 + row + srow) * DM + kb) + sswz,\
                       (void*)&As[buf][row][0]);                                      \
        }                                                                             \
        _Pragma("unroll")                                                             \
        for (int u = 0; u < 4; ++u) {                                                 \
            const int row = rbase + u * 8;                                            \
            load_lds16((const char*)(Wt + (size_t)(n0 + row + srow) * DM + kb) + sswz,\
                       (void*)&Bs[buf][row][0]);                                      \
        }                                                                             \
    } while (0)

// one K-half compute phase: 8 frag reads + 16 MFMA on buffer cb
#define GCOMPUTE(cb, ks)                                                              \
    do {                                                                              \
        bf16x8 af[4], bf[4];                                                          \
        _Pragma("unroll")                                                             \
        for (int mb = 0; mb < 4; ++mb) {                                              \
            const int row = wm * 64 + mb * 16 + c;                                    \
            const int off = ((ks) * 64 + g * 16) ^ (16 * (row & 7));                  \
            af[mb] = *reinterpret_cast<const bf16x8*>((const char*)&As[cb][row][0] + off); \
        }                                                                             \
        _Pragma("unroll")                                                             \
        for (int nb = 0; nb < 4; ++nb) {                                              \
            const int row = wn * 64 + nb * 16 + c;                                    \
            const int off = ((ks) * 64 + g * 16) ^ (16 * (row & 7));                  \
            bf[nb] = *reinterpret_cast<const bf16x8*>((const char*)&Bs[cb][row][0] + off); \
        }                                                                             \
        _Pragma("unroll")                                                             \
        for (int mb = 0; mb < 4; ++mb)                                                \
            _Pragma("unroll")                                                         \
            for (int nb = 0; nb < 4; ++nb)                                            \
                acc[mb][nb] = __builtin_amdgcn_mfma_f32_16x16x32_bf16(af[mb], bf[nb], acc[mb][nb], 0, 0, 0); \
    } while (0)

    f32x4 acc[4][4];
#pragma unroll
    for (int i = 0; i < 4; ++i)
#pragma unroll
        for (int j = 0; j < 4; ++j) { acc[i][j][0] = 0.f; acc[i][j][1] = 0.f; acc[i][j][2] = 0.f; acc[i][j][3] = 0.f; }

    GSTAGE(0, 0);

    for (int kt = 0; kt < GNT; ++kt) {
        const int cb = kt & 1;
        __syncthreads();            // drains GSTAGE(kt); orders last reads of cb^1
        GCOMPUTE(cb, 0);
        if (kt + 1 < GNT) GSTAGE(cb ^ 1, kt + 1);   // drain deferred to next barrier
        GCOMPUTE(cb, 1);
    }

    const int p   = n0 >> 10;
    const int nl0 = (n0 & 1023) + wn * 64;
    const float* bias = (p == 0) ? bq : (p == 1) ? bk : bv;

#pragma unroll
    for (int nb = 0; nb < 4; ++nb) {
        const int col = nl0 + nb * 16 + c;
        const float bv_ = bias[col];
#pragma unroll
        for (int mb = 0; mb < 4; ++mb) {
            const int mrow0 = m0 + wm * 64 + mb * 16 + 4 * g;
            if (p == 0) {
#pragma unroll
                for (int i = 0; i < 4; ++i)
                    Qw[(size_t)(mrow0 + i) * DM + col] = f2bf((acc[mb][nb][i] + bv_) * QSCALE);
            } else if (p == 1) {
#pragma unroll
                for (int i = 0; i < 4; ++i)
                    Kw[(size_t)(mrow0 + i) * DM + col] = f2bf(acc[mb][nb][i] + bv_);
            } else {
                const int hh = col >> 6, dd = col & 63;
                const int bb = mrow0 >> 11, ss = mrow0 & (SEQ - 1);
                ushort4 o;
                o.x = f2bf(acc[mb][nb][0] + bv_);
                o.y = f2bf(acc[mb][nb][1] + bv_);
                o.z = f2bf(acc[mb][nb][2] + bv_);
                o.w = f2bf(acc[mb][nb][3] + bv_);
                *reinterpret_cast<ushort4*>(&Vt[((size_t)(bb * NH + hh) * DH + dd) * SEQ + ss]) = o;
            }
        }
    }
#undef GSTAGE
#undef GCOMPUTE
}

// ---------------------------------------------------------------------------
// Kernel 2: flash attention (r11-verified, unchanged): 32x32x16 MFMA, swapped
// QK^T, in-register P via cvt_pk+permlane32_swap, exp2 softmax, XCD
// head-locality, single __syncthreads per K-tile with mid-iter prefetch.
// ---------------------------------------------------------------------------
__global__ __launch_bounds__(256, 3)
void attn_pipe(const unsigned short* __restrict__ Qw,
               const unsigned short* __restrict__ Kw,
               const unsigned short* __restrict__ Vt,
               float* __restrict__ O)
{
    __shared__ __align__(16) unsigned short Kt[2][64][64];   // [key][d], row-swizzled
    __shared__ __align__(16) unsigned short Vs[2][64][64];   // [d][key], row-swizzled
    __shared__ float Lbuf[4][32];

    const int t    = threadIdx.x;
    const int lane = t & 63;
    const int w    = t >> 6;        // wave 0..3
    const int q    = lane & 31;     // this lane's q-column (within wave tile)
    const int hi   = lane >> 5;     // half-wave

    // XCD head-locality: bid&7 = XCD; each XCD owns 8 whole heads x 16 tiles.
    const int bid = blockIdx.x;
    const int ii  = bid >> 3;                    // 0..127
    const int hd  = (bid & 7) * 8 + (ii >> 4);   // global head 0..63
    const int b   = hd >> 4;
    const int h   = hd & 15;
    const int q0  = (ii & 15) * 128;

    const size_t kqbase = ((size_t)b * SEQ) * DM + (size_t)h * DH;
    const size_t vbase  = ((size_t)(b * NH + h) * DH) * SEQ;

    // ---- Q B-frags (already scaled by 0.125*log2e) ----
    bf16x8 qf[4];
    {
        const unsigned short* qrow = Qw + kqbase + (size_t)(q0 + 32 * w + q) * DM;
#pragma unroll
        for (int ks = 0; ks < 4; ++ks)
            qf[ks] = *reinterpret_cast<const bf16x8*>(qrow + 16 * ks + 8 * hi);
    }

    f32x16 oacc[2];
#pragma unroll
    for (int dt = 0; dt < 2; ++dt)
#pragma unroll
        for (int i = 0; i < 16; ++i) oacc[dt][i] = 0.f;
    float lpart = 0.f;

    // staging lane geometry (8 rows x 128B per issue; XOR-16 source swizzle)
    const int srow = lane >> 3;
    const int sswz = ((lane & 7) * 16) ^ (16 * (srow & 7));
    const int r0   = w * 16;        // this wave stages rows [r0, r0+16)

#define STAGE_TILE(buf, kt)                                                          \
    do {                                                                             \
        _Pragma("unroll")                                                            \
        for (int u = 0; u < 2; ++u) {                                                \
            const int key = (kt) * 64 + r0 + u * 8 + srow;                           \
            load_lds16((const char*)(Kw + kqbase + (size_t)key * DM) + sswz,         \
                       (void*)&Kt[buf][r0 + u * 8][0]);                              \
        }                                                                            \
        _Pragma("unroll")                                                            \
        for (int u = 0; u < 2; ++u) {                                                \
            const int d = r0 + u * 8 + srow;                                         \
            load_lds16((const char*)(Vt + vbase + (size_t)d * SEQ + (kt) * 64) + sswz,\
                       (void*)&Vs[buf][r0 + u * 8][0]);                              \
        }                                                                            \
    } while (0)

    STAGE_TILE(0, 0);
    __syncthreads();   // prologue drain: tile 0 resident

    const int swzb = 16 * (lane & 7);   // read-side XOR (row&7 == lane&7 for our rows)

    for (int kt = 0; kt < NKT; ++kt) {
        const int cb = kt & 1;

        // ---- S^T = K·Q^T: two 32-key tiles ----
        f32x16 st[2];
#pragma unroll
        for (int kt2 = 0; kt2 < 2; ++kt2) {
            f32x16 z;
#pragma unroll
            for (int i = 0; i < 16; ++i) z[i] = 0.f;
#pragma unroll
            for (int ks = 0; ks < 4; ++ks) {
                const int off = (32 * ks + 16 * hi) ^ swzb;
                bf16x8 kf = *reinterpret_cast<const bf16x8*>(
                    (const char*)&Kt[cb][kt2 * 32 + q][0] + off);
                z = __builtin_amdgcn_mfma_f32_32x32x16_bf16(kf, qf[ks], z, 0, 0, 0);
            }
            st[kt2] = z;
        }

        // ---- lane-local softmax: exp2 + deferred l + pack to bf16 dwords ----
        unsigned Dw[2][8];
#pragma unroll
        for (int kt2 = 0; kt2 < 2; ++kt2)
#pragma unroll
            for (int j = 0; j < 8; ++j) {
                const float e0 = hexp2(st[kt2][2 * j]);
                const float e1 = hexp2(st[kt2][2 * j + 1]);
                lpart += e0 + e1;
                unsigned d;
                asm("v_cvt_pk_bf16_f32 %0, %1, %2" : "=v"(d) : "v"(e0), "v"(e1));
                Dw[kt2][j] = d;
            }

        // ---- assemble P A-frags (row=q, k=16ks+8hi..+7) via permlane32_swap ----
        bf16x8 pf[4];
#pragma unroll
        for (int ks = 0; ks < 4; ++ks) {
            const int kt2 = ks >> 1, lw = ks & 1;
            unsigned a0 = Dw[kt2][4 * lw + 0];
            unsigned a1 = Dw[kt2][4 * lw + 1];
            unsigned a2 = Dw[kt2][4 * lw + 2];
            unsigned a3 = Dw[kt2][4 * lw + 3];
            asm volatile("v_permlane32_swap_b32 %0, %1" : "+v"(a0), "+v"(a2));
            asm volatile("v_permlane32_swap_b32 %0, %1" : "+v"(a1), "+v"(a3));
            u32x4 tv; tv[0] = a0; tv[1] = a1; tv[2] = a2; tv[3] = a3;
            pf[ks] = __builtin_bit_cast(bf16x8, tv);
        }

        // ---- mid-iter prefetch: latency hides under PV below ----
        if (kt + 1 < NKT) STAGE_TILE(cb ^ 1, kt + 1);

        // ---- PV: oacc += P(32q x 64k) · V(64k x 64d), two 32-d tiles ----
#pragma unroll
        for (int dt = 0; dt < 2; ++dt)
#pragma unroll
            for (int ks = 0; ks < 4; ++ks) {
                const int off = (32 * ks + 16 * hi) ^ swzb;
                bf16x8 vf = *reinterpret_cast<const bf16x8*>(
                    (const char*)&Vs[cb][dt * 32 + q][0] + off);
                oacc[dt] = __builtin_amdgcn_mfma_f32_32x32x16_bf16(pf[ks], vf, oacc[dt], 0, 0, 0);
            }

        __syncthreads();   // single barrier: drains prefetch; orders cb reads
    }

    // ---- epilogue: l = own + partner halves; broadcast inv via tiny LDS ----
    {
        const float ltot = lpart + __shfl_xor(lpart, 32);
        if (lane < 32) Lbuf[w][q] = 1.0f / ltot;
    }

    float* obase = O + ((size_t)(b * SEQ + q0 + 32 * w)) * DM + h * DH;
#pragma unroll
    for (int j = 0; j < 4; ++j) {
        f32x4 iv = *reinterpret_cast<const f32x4*>(&Lbuf[w][8 * j + 4 * hi]);
#pragma unroll
        for (int i = 0; i < 4; ++i) {
            const int r   = 4 * j + i;
            const int row = 8 * j + 4 * hi + i;   // = crow(r, hi)
#pragma unroll
            for (int dt = 0; dt < 2; ++dt)
                obase[(size_t)row * DM + dt * 32 + q] = oacc[dt][r] * iv[i];
        }
    }
#undef STAGE_TILE
}

// ---------------------------------------------------------------------------
extern "C" void kernel_launch(void* const* d_in, const int* in_sizes, int n_in,
                              void* d_out, int out_size, void* d_ws, size_t ws_size,
                              hipStream_t stream) {
    const float* x  = (const float*)d_in[0];
    const float* Wq = (const float*)d_in[1];
    const float* bq = (const float*)d_in[2];
    const float* Wk = (const float*)d_in[3];
    const float* bk = (const float*)d_in[4];
    const float* Wv = (const float*)d_in[5];
    const float* bv = (const float*)d_in[6];
    float* out = (float*)d_out;

    unsigned short* q  = (unsigned short*)d_ws;
    unsigned short* k  = q  + (size_t)MTOT * DM;
    unsigned short* vt = k  + (size_t)MTOT * DM;
    unsigned short* xb = vt + (size_t)MTOT * DM;
    unsigned short* wt = xb + (size_t)MTOT * DM;

    xcvt<<<2048, 256, 0, stream>>>(x, xb, MTOT * DM / 8);
    wtcvt<<<dim3(16, 16, 3), 256, 0, stream>>>(Wq, Wk, Wv, wt);

    qkv_mfma<<<1536, 256, 0, stream>>>(xb, wt, bq, bk, bv, q, k, vt);

    attn_pipe<<<1024, 256, 0, stream>>>(q, k, vt, out);
}

// Round 14
// 168.918 us; speedup vs baseline: 1.0250x; 1.0250x over previous
//
#include <hip/hip_runtime.h>
#include <math.h>

// Problem constants (fixed by the reference)
#define DM   1024
#define SEQ  2048
#define BAT  4
#define NH   16
#define DH   64
#define MTOT (BAT*SEQ)   // 8192 rows
#define NKT  (SEQ/64)    // 32 key tiles

typedef __attribute__((ext_vector_type(8))) short bf16x8;   // 8 bf16 = 4 VGPR (MFMA A/B frag)
typedef __attribute__((ext_vector_type(4))) short bf16x4;
typedef __attribute__((ext_vector_type(4))) float f32x4;    // 16x16 MFMA C/D frag
typedef __attribute__((ext_vector_type(16))) float f32x16;  // 32x32 MFMA C/D frag
typedef __attribute__((ext_vector_type(4))) unsigned int u32x4;

// scores pre-scaled into exp2 domain: 1/sqrt(64) * log2(e)
#define QSCALE 0.18033688011112042f

static __device__ __forceinline__ unsigned short f2bf(float f) {
    union { float f; unsigned u; } x; x.f = f;
    unsigned r = x.u + 0x7fffu + ((x.u >> 16) & 1u);   // RNE
    return (unsigned short)(r >> 16);
}

// hardware exp2 (v_exp_f32) — avoid __exp2f, which collides with glibc math.h
static __device__ __forceinline__ float hexp2(float x) {
    return __builtin_amdgcn_exp2f(x);
}

static __device__ __forceinline__ void load_lds16(const void* g, void* l) {
    __builtin_amdgcn_global_load_lds(
        (const __attribute__((address_space(1))) unsigned int*)g,
        (__attribute__((address_space(3))) unsigned int*)l,
        16, 0, 0);
}

// ---------------------------------------------------------------------------
// Kernel 0a: x (fp32) -> bf16, elementwise
// ---------------------------------------------------------------------------
__global__ __launch_bounds__(256)
void xcvt(const float* __restrict__ x, unsigned short* __restrict__ out, int n8)
{
    for (int i = blockIdx.x * blockDim.x + threadIdx.x; i < n8; i += gridDim.x * blockDim.x) {
        float4 a = reinterpret_cast<const float4*>(x)[2 * i];
        float4 b = reinterpret_cast<const float4*>(x)[2 * i + 1];
        ushort4 lo, hi;
        lo.x = f2bf(a.x); lo.y = f2bf(a.y); lo.z = f2bf(a.z); lo.w = f2bf(a.w);
        hi.x = f2bf(b.x); hi.y = f2bf(b.y); hi.z = f2bf(b.z); hi.w = f2bf(b.w);
        reinterpret_cast<ushort4*>(out)[2 * i]     = lo;
        reinterpret_cast<ushort4*>(out)[2 * i + 1] = hi;
    }
}

// ---------------------------------------------------------------------------
// Kernel 0b: W[k][n] fp32 -> Wt[n][k] bf16 (per projection), Wt[3072][1024].
// ---------------------------------------------------------------------------
__global__ __launch_bounds__(256)
void wtcvt(const float* __restrict__ Wq, const float* __restrict__ Wk,
           const float* __restrict__ Wv, unsigned short* __restrict__ Wt)
{
    const float* W = (blockIdx.z == 0) ? Wq : (blockIdx.z == 1) ? Wk : Wv;
    unsigned short* out = Wt + (size_t)blockIdx.z * DM * DM;

    __shared__ float Ts[64][65];   // Ts[k][n]
    const int t  = threadIdx.x;
    const int k0 = blockIdx.y * 64;
    const int n0 = blockIdx.x * 64;

    const int r  = t >> 4;
    const int c4 = (t & 15) * 4;
#pragma unroll
    for (int u = 0; u < 4; ++u) {
        float4 v = *reinterpret_cast<const float4*>(&W[(size_t)(k0 + r + u * 16) * DM + n0 + c4]);
        Ts[r + u * 16][c4 + 0] = v.x;
        Ts[r + u * 16][c4 + 1] = v.y;
        Ts[r + u * 16][c4 + 2] = v.z;
        Ts[r + u * 16][c4 + 3] = v.w;
    }
    __syncthreads();

    const int n   = t >> 2;
    const int kk0 = (t & 3) * 16;
#pragma unroll
    for (int j = 0; j < 4; ++j) {
        ushort4 o;
        o.x = f2bf(Ts[kk0 + j * 4 + 0][n]);
        o.y = f2bf(Ts[kk0 + j * 4 + 1][n]);
        o.z = f2bf(Ts[kk0 + j * 4 + 2][n]);
        o.w = f2bf(Ts[kk0 + j * 4 + 3][n]);
        *reinterpret_cast<ushort4*>(&out[(size_t)(n0 + n) * DM + k0 + kk0 + j * 4]) = o;
    }
}

// ---------------------------------------------------------------------------
// Kernel 1: QKV projection GEMM, bf16 MFMA (16x16x32), fp32 accumulate.
// r10/r11-verified two-barrier structure, unchanged.
// ---------------------------------------------------------------------------
#define GBM 128
#define GBN 128
#define GBK 64
#define GNT (DM/GBK)

__global__ __launch_bounds__(256)
void qkv_mfma(const unsigned short* __restrict__ Xb,
              const unsigned short* __restrict__ Wt,
              const float* __restrict__ bq, const float* __restrict__ bk,
              const float* __restrict__ bv,
              unsigned short* __restrict__ Qw, unsigned short* __restrict__ Kw,
              unsigned short* __restrict__ Vt)
{
    __shared__ __align__(16) unsigned short As[2][GBM][GBK];
    __shared__ __align__(16) unsigned short Bs[2][GBN][GBK];

    const int t    = threadIdx.x;
    const int lane = t & 63;
    const int w    = t >> 6;
    const int g    = lane >> 4;
    const int c    = lane & 15;
    const int wm   = w >> 1;
    const int wn   = w & 1;

    const int cpx = gridDim.x >> 3;
    const int swz = (blockIdx.x & 7) * cpx + (blockIdx.x >> 3);
    const int tn  = swz % (3072 / GBN);
    const int tm  = swz / (3072 / GBN);
    const int m0  = tm * GBM;
    const int n0  = tn * GBN;

    const int srow  = lane >> 3;
    const int sswz  = ((lane & 7) * 16) ^ (16 * (srow & 7));
    const int rbase = w * 32;

#define GSTAGE(buf, kt)                                                               \
    do {                                                                              \
        const size_t kb = (size_t)(kt) * GBK;                                         \
        _Pragma("unroll")                                                             \
        for (int u = 0; u < 4; ++u) {                                                 \
            const int row = rbase + u * 8;                                            \
            load_lds16((const char*)(Xb + (size_t)(m0 + row + srow) * DM + kb) + sswz,\
                       (void*)&As[buf][row][0]);                                      \
        }                                                                             \
        _Pragma("unroll")                                                             \
        for (int u = 0; u < 4; ++u) {                                                 \
            const int row = rbase + u * 8;                                            \
            load_lds16((const char*)(Wt + (size_t)(n0 + row + srow) * DM + kb) + sswz,\
                       (void*)&Bs[buf][row][0]);                                      \
        }                                                                             \
    } while (0)

    f32x4 acc[4][4];
#pragma unroll
    for (int i = 0; i < 4; ++i)
#pragma unroll
        for (int j = 0; j < 4; ++j) { acc[i][j][0] = 0.f; acc[i][j][1] = 0.f; acc[i][j][2] = 0.f; acc[i][j][3] = 0.f; }

    GSTAGE(0, 0);

    for (int kt = 0; kt < GNT; ++kt) {
        const int cb = kt & 1;
        if (kt + 1 < GNT) GSTAGE(cb ^ 1, kt + 1);
        __syncthreads();

#pragma unroll
        for (int ks = 0; ks < 2; ++ks) {
            bf16x8 af[4], bf[4];
#pragma unroll
            for (int mb = 0; mb < 4; ++mb) {
                const int row = wm * 64 + mb * 16 + c;
                const int off = (ks * 64 + g * 16) ^ (16 * (row & 7));
                af[mb] = *reinterpret_cast<const bf16x8*>((const char*)&As[cb][row][0] + off);
            }
#pragma unroll
            for (int nb = 0; nb < 4; ++nb) {
                const int row = wn * 64 + nb * 16 + c;
                const int off = (ks * 64 + g * 16) ^ (16 * (row & 7));
                bf[nb] = *reinterpret_cast<const bf16x8*>((const char*)&Bs[cb][row][0] + off);
            }
#pragma unroll
            for (int mb = 0; mb < 4; ++mb)
#pragma unroll
                for (int nb = 0; nb < 4; ++nb)
                    acc[mb][nb] = __builtin_amdgcn_mfma_f32_16x16x32_bf16(af[mb], bf[nb], acc[mb][nb], 0, 0, 0);
        }

        __syncthreads();
    }

    const int p   = n0 >> 10;
    const int nl0 = (n0 & 1023) + wn * 64;
    const float* bias = (p == 0) ? bq : (p == 1) ? bk : bv;

#pragma unroll
    for (int nb = 0; nb < 4; ++nb) {
        const int col = nl0 + nb * 16 + c;
        const float bv_ = bias[col];
#pragma unroll
        for (int mb = 0; mb < 4; ++mb) {
            const int mrow0 = m0 + wm * 64 + mb * 16 + 4 * g;
            if (p == 0) {
#pragma unroll
                for (int i = 0; i < 4; ++i)
                    Qw[(size_t)(mrow0 + i) * DM + col] = f2bf((acc[mb][nb][i] + bv_) * QSCALE);
            } else if (p == 1) {
#pragma unroll
                for (int i = 0; i < 4; ++i)
                    Kw[(size_t)(mrow0 + i) * DM + col] = f2bf(acc[mb][nb][i] + bv_);
            } else {
                const int hh = col >> 6, dd = col & 63;
                const int bb = mrow0 >> 11, ss = mrow0 & (SEQ - 1);
                ushort4 o;
                o.x = f2bf(acc[mb][nb][0] + bv_);
                o.y = f2bf(acc[mb][nb][1] + bv_);
                o.z = f2bf(acc[mb][nb][2] + bv_);
                o.w = f2bf(acc[mb][nb][3] + bv_);
                *reinterpret_cast<ushort4*>(&Vt[((size_t)(bb * NH + hh) * DH + dd) * SEQ + ss]) = o;
            }
        }
    }
#undef GSTAGE
}

// ---------------------------------------------------------------------------
// Kernel 2: flash attention — EXACT r11-verified kernel (passed, 88.9 µs)
// plus T5 s_setprio(1)/(0) around the QK^T and PV MFMA clusters only.
// setprio is a pure CU-scheduler hint (no memory semantics) — zero
// correctness risk; m191 measured +4-7% on multi-wave attention.
// ---------------------------------------------------------------------------
__global__ __launch_bounds__(256, 3)
void attn_pipe(const unsigned short* __restrict__ Qw,
               const unsigned short* __restrict__ Kw,
               const unsigned short* __restrict__ Vt,
               float* __restrict__ O)
{
    __shared__ __align__(16) unsigned short Kt[2][64][64];   // [key][d], row-swizzled
    __shared__ __align__(16) unsigned short Vs[2][64][64];   // [d][key], row-swizzled
    __shared__ float Lbuf[4][32];

    const int t    = threadIdx.x;
    const int lane = t & 63;
    const int w    = t >> 6;        // wave 0..3
    const int q    = lane & 31;     // this lane's q-column (within wave tile)
    const int hi   = lane >> 5;     // half-wave

    // XCD head-locality: bid&7 = XCD; each XCD owns 8 whole heads x 16 tiles.
    const int bid = blockIdx.x;
    const int ii  = bid >> 3;                    // 0..127
    const int hd  = (bid & 7) * 8 + (ii >> 4);   // global head 0..63
    const int b   = hd >> 4;
    const int h   = hd & 15;
    const int q0  = (ii & 15) * 128;

    const size_t kqbase = ((size_t)b * SEQ) * DM + (size_t)h * DH;
    const size_t vbase  = ((size_t)(b * NH + h) * DH) * SEQ;

    // ---- Q B-frags (already scaled by 0.125*log2e) ----
    bf16x8 qf[4];
    {
        const unsigned short* qrow = Qw + kqbase + (size_t)(q0 + 32 * w + q) * DM;
#pragma unroll
        for (int ks = 0; ks < 4; ++ks)
            qf[ks] = *reinterpret_cast<const bf16x8*>(qrow + 16 * ks + 8 * hi);
    }

    f32x16 oacc[2];
#pragma unroll
    for (int dt = 0; dt < 2; ++dt)
#pragma unroll
        for (int i = 0; i < 16; ++i) oacc[dt][i] = 0.f;
    float lpart = 0.f;

    // staging lane geometry (8 rows x 128B per issue; XOR-16 source swizzle)
    const int srow = lane >> 3;
    const int sswz = ((lane & 7) * 16) ^ (16 * (srow & 7));
    const int r0   = w * 16;        // this wave stages rows [r0, r0+16)

#define STAGE_TILE(buf, kt)                                                          \
    do {                                                                             \
        _Pragma("unroll")                                                            \
        for (int u = 0; u < 2; ++u) {                                                \
            const int key = (kt) * 64 + r0 + u * 8 + srow;                           \
            load_lds16((const char*)(Kw + kqbase + (size_t)key * DM) + sswz,         \
                       (void*)&Kt[buf][r0 + u * 8][0]);                              \
        }                                                                            \
        _Pragma("unroll")                                                            \
        for (int u = 0; u < 2; ++u) {                                                \
            const int d = r0 + u * 8 + srow;                                         \
            load_lds16((const char*)(Vt + vbase + (size_t)d * SEQ + (kt) * 64) + sswz,\
                       (void*)&Vs[buf][r0 + u * 8][0]);                              \
        }                                                                            \
    } while (0)

    STAGE_TILE(0, 0);
    __syncthreads();   // prologue drain: tile 0 resident

    const int swzb = 16 * (lane & 7);   // read-side XOR (row&7 == lane&7 for our rows)

    for (int kt = 0; kt < NKT; ++kt) {
        const int cb = kt & 1;

        // ---- S^T = K·Q^T: two 32-key tiles ----
        f32x16 st[2];
        __builtin_amdgcn_s_setprio(1);
#pragma unroll
        for (int kt2 = 0; kt2 < 2; ++kt2) {
            f32x16 z;
#pragma unroll
            for (int i = 0; i < 16; ++i) z[i] = 0.f;
#pragma unroll
            for (int ks = 0; ks < 4; ++ks) {
                const int off = (32 * ks + 16 * hi) ^ swzb;
                bf16x8 kf = *reinterpret_cast<const bf16x8*>(
                    (const char*)&Kt[cb][kt2 * 32 + q][0] + off);
                z = __builtin_amdgcn_mfma_f32_32x32x16_bf16(kf, qf[ks], z, 0, 0, 0);
            }
            st[kt2] = z;
        }
        __builtin_amdgcn_s_setprio(0);

        // ---- lane-local softmax: exp2 + deferred l + pack to bf16 dwords ----
        unsigned Dw[2][8];
#pragma unroll
        for (int kt2 = 0; kt2 < 2; ++kt2)
#pragma unroll
            for (int j = 0; j < 8; ++j) {
                const float e0 = hexp2(st[kt2][2 * j]);
                const float e1 = hexp2(st[kt2][2 * j + 1]);
                lpart += e0 + e1;
                unsigned d;
                asm("v_cvt_pk_bf16_f32 %0, %1, %2" : "=v"(d) : "v"(e0), "v"(e1));
                Dw[kt2][j] = d;
            }

        // ---- assemble P A-frags (row=q, k=16ks+8hi..+7) via permlane32_swap ----
        bf16x8 pf[4];
#pragma unroll
        for (int ks = 0; ks < 4; ++ks) {
            const int kt2 = ks >> 1, lw = ks & 1;
            unsigned a0 = Dw[kt2][4 * lw + 0];
            unsigned a1 = Dw[kt2][4 * lw + 1];
            unsigned a2 = Dw[kt2][4 * lw + 2];
            unsigned a3 = Dw[kt2][4 * lw + 3];
            asm volatile("v_permlane32_swap_b32 %0, %1" : "+v"(a0), "+v"(a2));
            asm volatile("v_permlane32_swap_b32 %0, %1" : "+v"(a1), "+v"(a3));
            u32x4 tv; tv[0] = a0; tv[1] = a1; tv[2] = a2; tv[3] = a3;
            pf[ks] = __builtin_bit_cast(bf16x8, tv);
        }

        // ---- mid-iter prefetch: latency hides under PV below ----
        if (kt + 1 < NKT) STAGE_TILE(cb ^ 1, kt + 1);

        // ---- PV: oacc += P(32q x 64k) · V(64k x 64d), two 32-d tiles ----
        __builtin_amdgcn_s_setprio(1);
#pragma unroll
        for (int dt = 0; dt < 2; ++dt)
#pragma unroll
            for (int ks = 0; ks < 4; ++ks) {
                const int off = (32 * ks + 16 * hi) ^ swzb;
                bf16x8 vf = *reinterpret_cast<const bf16x8*>(
                    (const char*)&Vs[cb][dt * 32 + q][0] + off);
                oacc[dt] = __builtin_amdgcn_mfma_f32_32x32x16_bf16(pf[ks], vf, oacc[dt], 0, 0, 0);
            }
        __builtin_amdgcn_s_setprio(0);

        __syncthreads();   // single barrier: drains prefetch; orders cb reads
    }

    // ---- epilogue: l = own + partner halves; broadcast inv via tiny LDS ----
    {
        const float ltot = lpart + __shfl_xor(lpart, 32);
        if (lane < 32) Lbuf[w][q] = 1.0f / ltot;
    }

    float* obase = O + ((size_t)(b * SEQ + q0 + 32 * w)) * DM + h * DH;
#pragma unroll
    for (int j = 0; j < 4; ++j) {
        f32x4 iv = *reinterpret_cast<const f32x4*>(&Lbuf[w][8 * j + 4 * hi]);
#pragma unroll
        for (int i = 0; i < 4; ++i) {
            const int r   = 4 * j + i;
            const int row = 8 * j + 4 * hi + i;   // = crow(r, hi)
#pragma unroll
            for (int dt = 0; dt < 2; ++dt)
                obase[(size_t)row * DM + dt * 32 + q] = oacc[dt][r] * iv[i];
        }
    }
#undef STAGE_TILE
}

// ---------------------------------------------------------------------------
extern "C" void kernel_launch(void* const* d_in, const int* in_sizes, int n_in,
                              void* d_out, int out_size, void* d_ws, size_t ws_size,
                              hipStream_t stream) {
    const float* x  = (const float*)d_in[0];
    const float* Wq = (const float*)d_in[1];
    const float* bq = (const float*)d_in[2];
    const float* Wk = (const float*)d_in[3];
    const float* bk = (const float*)d_in[4];
    const float* Wv = (const float*)d_in[5];
    const float* bv = (const float*)d_in[6];
    float* out = (float*)d_out;

    unsigned short* q  = (unsigned short*)d_ws;
    unsigned short* k  = q  + (size_t)MTOT * DM;
    unsigned short* vt = k  + (size_t)MTOT * DM;
    unsigned short* xb = vt + (size_t)MTOT * DM;
    unsigned short* wt = xb + (size_t)MTOT * DM;

    xcvt<<<2048, 256, 0, stream>>>(x, xb, MTOT * DM / 8);
    wtcvt<<<dim3(16, 16, 3), 256, 0, stream>>>(Wq, Wk, Wv, wt);

    qkv_mfma<<<1536, 256, 0, stream>>>(xb, wt, bq, bk, bv, q, k, vt);

    attn_pipe<<<1024, 256, 0, stream>>>(q, k, vt, out);
}